// Round 5
// baseline (306.127 us; speedup 1.0000x reference)
//
#include <hip/hip_runtime.h>
#include <stddef.h>

// out[n,j,h,w] = sum_{k,i} x[n,i,(h+55)%56, srccol(k,w)] * w[j,k,i]
//   tap k=0: valid w>=1,  col (w+54)%56
//   tap k=1: always,      col (w+55)%56
//   tap k=2: valid w<=54, col w
// GEMM view: M=32 (j), K=384 (tap*128+i), N=spatial. bf16 MFMA 16x16x32.
// R5 = R4 resubmitted (container infra failure, no signal).
// Persistent double-buffered pipeline. Theory: previous structure was
// phase-locked (stage -> sync -> compute) so HBM idled ~24% during compute;
// 3 intra-phase optimizations were all neutral. Now: grid=256 (1 block/CU),
// 1024 thr (16 waves = 4/SIMD), block owns (n, 7 consecutive h-tiles).
// LDS = 2 x XT (124KB) + packed weights (25KB -> A-frags via ds_read so
// compute uses lgkmcnt only; in-order vmcnt would stall compute on the
// prefetch loads). Per tile: issue next tile's 8 float4 loads FIRST,
// compute current tile (LDS+MFMA only), then vmcnt+pack+ds_write other
// buffer, one barrier. HBM stays busy through the compute phase.

#define C_IN   128
#define C_OUT  32
#define HH     56
#define WW     56
#define HW     3136
#define KTOT   384
#define WSTRIDE 392              // padded K-stride for weights (bf16 elems)
#define XSTRIDE 136              // ushorts per col (272B = 17x16B -> bank-balanced b128 reads)
#define XROWSZ (57 * XSTRIDE)    // one source row: 56 real cols + zero col 56
#define NT     7                 // h-tiles per block

typedef short bf16x8 __attribute__((ext_vector_type(8)));
typedef float f32x4  __attribute__((ext_vector_type(4)));

static __device__ __forceinline__ unsigned short f2b(float f) {
    unsigned u = __builtin_bit_cast(unsigned, f);
    unsigned r = u + 0x7FFFu + ((u >> 16) & 1u);   // RNE
    return (unsigned short)(r >> 16);
}

static __device__ __forceinline__ unsigned pk2(float lo, float hi) {
    unsigned r;
    asm("v_cvt_pk_bf16_f32 %0, %1, %2" : "=v"(r) : "v"(lo), "v"(hi));  // RNE
    return r;
}

__global__ void pack_w_kernel(const float* __restrict__ w, unsigned short* __restrict__ ws) {
    int idx = blockIdx.x * 256 + threadIdx.x;
    if (idx < C_OUT * WSTRIDE) {
        int j = idx / WSTRIDE;
        int r = idx % WSTRIDE;
        ws[idx] = f2b(r < KTOT ? w[j * KTOT + r] : 0.0f);
    }
}

__global__ __launch_bounds__(1024, 4)
void conv_mfma_kernel(const float* __restrict__ x, const unsigned short* __restrict__ ws,
                      float* __restrict__ out) {
    const int bid  = blockIdx.x;
    const int n    = bid >> 1;
    const int half = bid & 1;          // h-tiles half*7 .. half*7+6
    const int tid  = threadIdx.x;
    const int lane = tid & 63;
    const int grp  = tid >> 6;         // 0..15

    // [2 bufs][4 src rows][57 cols][128 ch] + weights[32][392]  = 149120 B
    __shared__ __align__(16) unsigned short SH[8 * XROWSZ + C_OUT * WSTRIDE];
    unsigned short* const WSL = SH + 8 * XROWSZ;

    // zero col 56 of 4 rows in both buffers: 2*4*17 = 136 uint4
    if (tid < 136) {
        int b = tid / 68, r2 = (tid % 68) / 17, off = (tid % 17) * 8;
        *(uint4*)&SH[(b * 4 + r2) * XROWSZ + WW * XSTRIDE + off] = make_uint4(0, 0, 0, 0);
    }
    // copy packed weights to LDS: 12544 ushorts = 1568 uint4
    for (int i = tid; i < (C_OUT * WSTRIDE) / 8; i += 1024)
        ((uint4*)WSL)[i] = ((const uint4*)ws)[i];

    // ---- per-lane staging geometry: lane q<56 -> (r=q/14, c4=q%14),
    //      channels ch0..ch0+7 (ch0 = grp*8). One wave-inst = 896B granule.
    const int q   = lane;
    const int rs  = q / 14;
    const int c4  = q % 14;
    const int ch0 = grp * 8;
    const bool act = (q < WW);
    const float* xb = x + (size_t)n * (C_IN * HW) + (size_t)ch0 * HW + (size_t)(c4 * 4);

    // ---- per-lane compute geometry: wave -> row rr, col-quarter qt ----
    const int l15 = lane & 15;
    const int kb  = (lane >> 4) * 8;
    const int rr  = grp >> 2;
    const int qt  = grp & 3;
    const int nn  = qt * 16 + l15;
    int cco[3];
    cco[0] = (nn >= 1 && nn <= 55) ? (nn + 54) % WW : WW;
    cco[1] = (nn <= 55) ? (nn + 55) % WW : WW;
    cco[2] = (nn <= 54) ? nn : WW;
    const int bo0 = rr * XROWSZ + cco[0] * XSTRIDE + kb;
    const int bo1 = rr * XROWSZ + cco[1] * XSTRIDE + kb;
    const int bo2 = rr * XROWSZ + cco[2] * XSTRIDE + kb;
    const unsigned short* wp = WSL + l15 * WSTRIDE + kb;
    const int j0 = (lane >> 4) * 4;
    float* const outb = out + (size_t)n * (C_OUT * HW);

    // ---- prologue: stage tile 0 into buf 0 ----
    {
        const int h0 = (half * NT) * 4;
        const int hs = (h0 + 55 + rs) % HH;
        f32x4 v[8];
        if (act) {
            const float* s0 = xb + (size_t)hs * WW;
#pragma unroll
            for (int cc = 0; cc < 8; ++cc)
                v[cc] = *(const f32x4*)(s0 + (size_t)cc * HW);
            unsigned short* dstc = SH + rs * XROWSZ + (c4 * 4) * XSTRIDE + ch0;
#pragma unroll
            for (int vc = 0; vc < 4; ++vc) {
                uint4 w128;
                w128.x = pk2(v[0][vc], v[1][vc]);
                w128.y = pk2(v[2][vc], v[3][vc]);
                w128.z = pk2(v[4][vc], v[5][vc]);
                w128.w = pk2(v[6][vc], v[7][vc]);
                *(uint4*)(dstc + vc * XSTRIDE) = w128;
            }
        }
    }
    __syncthreads();

    // ---- main pipeline over 7 tiles ----
    for (int t = 0; t < NT; ++t) {
        // 1) issue next tile's global loads (in flight through compute)
        f32x4 v[8];
        if (t + 1 < NT && act) {
            const int h0n = (half * NT + t + 1) * 4;
            const int hsn = (h0n + 55 + rs) % HH;
            const float* s0 = xb + (size_t)hsn * WW;
#pragma unroll
            for (int cc = 0; cc < 8; ++cc)
                v[cc] = *(const f32x4*)(s0 + (size_t)cc * HW);
        }

        // 2) compute tile t from buf[t&1]  (pure LDS + MFMA: lgkmcnt only)
        const unsigned short* Xb = SH + (t & 1) * 4 * XROWSZ;
        f32x4 acc0 = (f32x4){0.f, 0.f, 0.f, 0.f};
        f32x4 acc1 = (f32x4){0.f, 0.f, 0.f, 0.f};
#pragma unroll
        for (int c = 0; c < 12; ++c) {
            const int tap = c >> 2;
            const int ib  = (c & 3) * 32;
            bf16x8 A0 = *(const bf16x8*)(wp + c * 32);
            bf16x8 A1 = *(const bf16x8*)(wp + 16 * WSTRIDE + c * 32);
            const unsigned short* bpt = Xb + (tap == 0 ? bo0 : tap == 1 ? bo1 : bo2);
            bf16x8 B = *(const bf16x8*)(bpt + ib);
            acc0 = __builtin_amdgcn_mfma_f32_16x16x32_bf16(A0, B, acc0, 0, 0, 0);
            acc1 = __builtin_amdgcn_mfma_f32_16x16x32_bf16(A1, B, acc1, 0, 0, 0);
        }

        // epilogue: C/D layout col=lane&15 (w), row=(lane>>4)*4+reg (j)
        {
            const int h = (half * NT + t) * 4 + rr;
            float* ob = outb + (size_t)h * WW;
            if (nn < WW) {
#pragma unroll
                for (int r4 = 0; r4 < 4; ++r4) {
                    ob[(size_t)(j0 + r4) * HW + nn]      = acc0[r4];
                    ob[(size_t)(j0 + r4 + 16) * HW + nn] = acc1[r4];
                }
            }
        }

        // 3) drain prefetch, pack into buf[(t+1)&1], barrier
        if (t + 1 < NT) {
            if (act) {
                unsigned short* dstc = SH + ((t + 1) & 1) * 4 * XROWSZ
                                     + rs * XROWSZ + (c4 * 4) * XSTRIDE + ch0;
#pragma unroll
                for (int vc = 0; vc < 4; ++vc) {
                    uint4 w128;
                    w128.x = pk2(v[0][vc], v[1][vc]);
                    w128.y = pk2(v[2][vc], v[3][vc]);
                    w128.z = pk2(v[4][vc], v[5][vc]);
                    w128.w = pk2(v[6][vc], v[7][vc]);
                    *(uint4*)(dstc + vc * XSTRIDE) = w128;
                }
            }
            __syncthreads();
        }
    }
}

extern "C" void kernel_launch(void* const* d_in, const int* in_sizes, int n_in,
                              void* d_out, int out_size, void* d_ws, size_t ws_size,
                              hipStream_t stream) {
    const float* x = (const float*)d_in[0];
    const float* w = (const float*)d_in[1];
    float* out = (float*)d_out;
    unsigned short* ws = (unsigned short*)d_ws;   // 32*392*2 = 25088 B needed

    pack_w_kernel<<<(C_OUT * WSTRIDE + 255) / 256, 256, 0, stream>>>(w, ws);
    conv_mfma_kernel<<<dim3(256), dim3(1024), 0, stream>>>(x, ws, out);
}